// Round 19
// baseline (208.701 us; speedup 1.0000x reference)
//
#include <hip/hip_runtime.h>
#include <math.h>

typedef __bf16 bf16_t;
typedef __bf16 bf16x8 __attribute__((ext_vector_type(8)));
typedef __bf16 bf16x4 __attribute__((ext_vector_type(4)));
typedef float f32x4 __attribute__((ext_vector_type(4)));

namespace {
constexpr int kB = 16;
constexpr int kT = 120;
constexpr int kP = 96;
constexpr int kD = 128;
constexpr int kBT = kB * kT;        // 1920
constexpr int kPP = kP * kP;        // 9216
constexpr int kPD = kP * kD;        // 12288
constexpr long long kND = (long long)kBT * kPP;  // 17,694,720

// k_front grid partition (r9 structure; stats doubled to fill tail phase)
constexpr int TIN_BLOCKS = (kPD / 64) * kB;       // 3072
constexpr int PREP_BLOCKS = 128;
constexpr int STATS_BLOCKS = 2048;
constexpr int FRONT_BLOCKS = TIN_BLOCKS + PREP_BLOCKS + STATS_BLOCKS;  // 5248

// k_gcn LDS layout (bytes) — round-7/9 structure (known-good):
constexpr int YS = 136;
constexpr int HS = 104;
constexpr int OS = 132;
constexpr int AS = 104;
constexpr int HT_OFF = 26112;
constexpr int AL_OFF = 52736;
constexpr int MROW_OFF = 72704;
constexpr int DIS_OFF = 73088;
constexpr int SMEM_B = 73472;       // -> 2 blocks/CU by LDS
}

__device__ __forceinline__ f32x4 mfma16(bf16x8 a, bf16x8 b, f32x4 c) {
    return __builtin_amdgcn_mfma_f32_16x16x32_bf16(a, b, c, 0, 0, 0);
}

// ---------------------------------------------------------------------------
// Kernel 1 (k_front): heterogeneous grid fusing three independent jobs.
//   blocks [0, 3072)      : transpose-in, x loads NON-TEMPORAL (r17-proven)
//   blocks [3072, 3200)   : W transpose->bf16; first block canonicalizes mask
//   blocks [3200, 5248)   : masked distance stats (NORMAL loads: dist re-read
//                           by k_gcn). 2048 blocks fill the tail phase.
// stats accumulators zeroed by hipMemsetAsync; stats blocks dispatch LAST.
// ---------------------------------------------------------------------------
__global__ __launch_bounds__(256) void k_front(const float* __restrict__ x,
                                               bf16_t* __restrict__ y,
                                               const float* __restrict__ dist,
                                               const unsigned char* __restrict__ mraw,
                                               int* __restrict__ mask,
                                               double* __restrict__ stats,
                                               const float* __restrict__ W,
                                               bf16_t* __restrict__ wT) {
    __shared__ __align__(16) char sm[31104];
    const int bid = blockIdx.x;
    const int tid = threadIdx.x;

    if (bid < TIN_BLOCKS) {
        // ---- transpose-in role ----
        float* tile = (float*)sm;                  // [64][121] f32 = 30976 B
        int b = bid / (kPD / 64), pd0 = (bid % (kPD / 64)) * 64;
        const float* xb = x + ((long long)b * kPD + pd0) * kT;
        #pragma unroll
        for (int k = 0; k < 8; ++k) {
            int idx = k * 256 + tid;               // < 1920 = 64 rows * 30 float4
            if (idx < 1920) {
                int r = idx / 30, c = idx - r * 30;
                f32x4 v = __builtin_nontemporal_load((const f32x4*)(xb + r * kT + c * 4));
                tile[r * 121 + c * 4 + 0] = v[0];
                tile[r * 121 + c * 4 + 1] = v[1];
                tile[r * 121 + c * 4 + 2] = v[2];
                tile[r * 121 + c * 4 + 3] = v[3];
            }
        }
        __syncthreads();
        bf16_t* yb = y + (long long)b * kT * kPD + pd0;
        #pragma unroll
        for (int k = 0; k < 4; ++k) {
            int idx = k * 256 + tid;               // < 960 = 120 t * 8 dgroups
            if (idx < 960) {
                int t = idx >> 3, dg = idx & 7;
                bf16x8 o;
                #pragma unroll
                for (int j = 0; j < 8; ++j) o[j] = (bf16_t)tile[(dg * 8 + j) * 121 + t];
                *(bf16x8*)(yb + (long long)t * kPD + dg * 8) = o;
            }
        }
    } else if (bid < TIN_BLOCKS + PREP_BLOCKS) {
        // ---- W-prep role ----
        int pb = bid - TIN_BLOCKS;                 // 0..127
        int l = pb >> 6;
        int idx = (pb & 63) * 256 + tid;           // 0..16383
        int n = idx >> 7, k = idx & 127;
        wT[l * 16384 + n * 128 + k] = (bf16_t)W[l * 16384 + k * 128 + n];

        if (pb == 0) {
            const unsigned int* u32 = (const unsigned int*)mraw;
            unsigned int w0 = u32[0];
            int mode;
            if (w0 == 0x01010101u) mode = 0;       // 1-byte bool
            else if (w0 == 1u) mode = 1;           // int32
            else mode = 2;                          // float32
            for (int i = tid; i < kB * kP; i += 256) {
                int v;
                if (mode == 0)      v = (mraw[i] != 0);
                else if (mode == 1) v = (u32[i] != 0);
                else                v = (((const float*)mraw)[i] != 0.0f);
                mask[i] = v;
            }
        }
    } else {
        // ---- stats role (self-computes mask from mraw; no dependency) ----
        int sb = bid - TIN_BLOCKS - PREP_BLOCKS;   // 0..2047
        int* ml = (int*)sm;                        // [1536] = 6144 B
        double* sh = (double*)(sm + 6144);         // [256]  = 2048 B
        {
            const unsigned int* u32 = (const unsigned int*)mraw;
            unsigned int w0 = u32[0];
            int mode;
            if (w0 == 0x01010101u) mode = 0;
            else if (w0 == 1u) mode = 1;
            else mode = 2;
            for (int i = tid; i < kB * kP; i += 256) {
                int v;
                if (mode == 0)      v = (mraw[i] != 0);
                else if (mode == 1) v = (u32[i] != 0);
                else                v = (((const float*)mraw)[i] != 0.0f);
                ml[i] = v;
            }
        }
        __syncthreads();

        long long n4 = kND / 4;
        long long stride = (long long)STATS_BLOCKS * 256;
        double s = 0.0, s2 = 0.0;
        int cnt = 0;
        for (long long i4 = (long long)sb * 256 + tid; i4 < n4; i4 += stride) {
            int q0 = 4 * (int)(i4 % 24);
            long long r = i4 / 24;
            int p = (int)(r % 96);
            int b = (int)((r / 96) / kT);
            const int* mb = ml + b * kP;
            if (mb[p]) {
                float4 d4 = *(const float4*)(dist + i4 * 4);
                if (mb[q0 + 0]) { s += d4.x; s2 += (double)d4.x * d4.x; cnt++; }
                if (mb[q0 + 1]) { s += d4.y; s2 += (double)d4.y * d4.y; cnt++; }
                if (mb[q0 + 2]) { s += d4.z; s2 += (double)d4.z * d4.z; cnt++; }
                if (mb[q0 + 3]) { s += d4.w; s2 += (double)d4.w * d4.w; cnt++; }
            }
        }
        sh[tid] = s; __syncthreads();
        for (int off = 128; off > 0; off >>= 1) { if (tid < off) sh[tid] += sh[tid + off]; __syncthreads(); }
        if (tid == 0) atomicAdd(&stats[0], sh[0]);
        __syncthreads();
        sh[tid] = s2; __syncthreads();
        for (int off = 128; off > 0; off >>= 1) { if (tid < off) sh[tid] += sh[tid + off]; __syncthreads(); }
        if (tid == 0) atomicAdd(&stats[1], sh[0]);
        __syncthreads();
        sh[tid] = (double)cnt; __syncthreads();
        for (int off = 128; off > 0; off >>= 1) { if (tid < off) sh[tid] += sh[tid + off]; __syncthreads(); }
        if (tid == 0) atomicAdd(&stats[2], sh[0]);
    }
}

// ---------------------------------------------------------------------------
// Kernel 3: transpose out, y (B, T, PD) bf16 -> out (B, PD, T) f32.
// y loads and out stores NON-TEMPORAL (both dead after this kernel).
// ---------------------------------------------------------------------------
__global__ __launch_bounds__(256) void k_tout(const bf16_t* __restrict__ y,
                                              float* __restrict__ out) {
    __shared__ float tile[64 * 121];
    int b = blockIdx.y, pd0 = blockIdx.x * 64;
    int tid = threadIdx.x;
    const bf16_t* yb = y + (long long)b * kT * kPD + pd0;
    #pragma unroll
    for (int k = 0; k < 4; ++k) {
        int idx = k * 256 + tid;
        if (idx < 960) {
            int t = idx >> 3, dg = idx & 7;
            bf16x8 v = __builtin_nontemporal_load(
                (const bf16x8*)(yb + (long long)t * kPD + dg * 8));
            #pragma unroll
            for (int j = 0; j < 8; ++j) tile[(dg * 8 + j) * 121 + t] = (float)v[j];
        }
    }
    __syncthreads();
    float* ob = out + ((long long)b * kPD + pd0) * kT;
    #pragma unroll
    for (int k = 0; k < 8; ++k) {
        int idx = k * 256 + tid;
        if (idx < 1920) {
            int r = idx / 30, c = idx - r * 30;
            f32x4 v;
            v[0] = tile[r * 121 + c * 4 + 0];
            v[1] = tile[r * 121 + c * 4 + 1];
            v[2] = tile[r * 121 + c * 4 + 2];
            v[3] = tile[r * 121 + c * 4 + 3];
            __builtin_nontemporal_store(v, (f32x4*)(ob + r * kT + c * 4));
        }
    }
}

// ---------------------------------------------------------------------------
// Kernel 2: fused adjacency + 2-layer GCN — r7/r9 barrier skeleton, plus:
//  * W fragments for BOTH layers prefetched before B0 (drain folds into
//    B0's existing vmcnt wait; deletes two mid-kernel load stalls)
//  * single-pass LN reduction (var = E[v^2] - mu^2; eps dominates)
// ---------------------------------------------------------------------------
__global__ __launch_bounds__(512, 2) void k_gcn(bf16_t* __restrict__ y,
                                                const float* __restrict__ dist,
                                                const int* __restrict__ mask,
                                                const double* __restrict__ stats,
                                                const bf16_t* __restrict__ wT,
                                                const float* __restrict__ bias,
                                                const float* __restrict__ gamma,
                                                const float* __restrict__ beta) {
    __shared__ __align__(16) char smem[SMEM_B];
    bf16_t* yL  = (bf16_t*)smem;                  // [96][YS]
    bf16_t* hT  = (bf16_t*)(smem + HT_OFF);       // [128][HS] (union)
    bf16_t* oLb = (bf16_t*)(smem + HT_OFF);       // [96][OS]  (union)
    float*  aT  = (float*)smem;                   // [96][100] adj phase only
    bf16_t* aL  = (bf16_t*)(smem + AL_OFF);       // [96][AS]
    float* mrowf = (float*)(smem + MROW_OFF);     // [96]
    float* dis   = (float*)(smem + DIS_OFF);      // [96]

    const int tid = threadIdx.x;
    const int tx = tid & 15, ty = tid >> 4;       // ty 0..31 (3 rows each)
    const int lane = tid & 63, w = tid >> 6;      // w 0..7
    const int wm = w >> 2, wn = w & 3;            // 2x4 wave grid
    const int fc = lane & 15, fg = lane >> 4;     // MFMA frag coords
    const int bt = blockIdx.x, b = bt / kT;
    const int d0 = tx * 8;

    bf16_t* ybt = y + (size_t)bt * kPD;
    const float* dbt = dist + (size_t)bt * kPP;

    // W fragments for BOTH layers -> registers (issued before B0; L2-resident,
    // drained by B0's existing vmcnt wait). 64 VGPRs.
    bf16x8 wf[2][4][2];
    #pragma unroll
    for (int l = 0; l < 2; ++l) {
        const bf16_t* wTl = wT + l * kD * kD;
        #pragma unroll
        for (int kt = 0; kt < 4; ++kt) {
            wf[l][kt][0] = *(const bf16x8*)(wTl + ((wn * 2 + 0) * 16 + fc) * kD + kt * 32 + fg * 8);
            wf[l][kt][1] = *(const bf16x8*)(wTl + ((wn * 2 + 1) * 16 + fc) * kD + kt * 32 + fg * 8);
        }
    }

    if (tid < kP) mrowf[tid] = (float)mask[b * kP + tid];

    // sigma -> 1/(2 sigma^2)  (tiny, L2-resident)
    double sn = stats[2];
    double mean = stats[0] / sn;
    double var = (stats[1] - sn * mean * mean) / (sn - 1.0);
    double sg = sqrt(var) + 1e-8;
    float inv2s2 = (float)(1.0 / (2.0 * sg * sg));

    __syncthreads();   // [B0] mrowf ready (drains mask + wf loads)

    // ---- adj phase: aT = exp(-d^2/(2s^2))*vm + eye*mask ----
    #pragma unroll
    for (int k = 0; k < 5; ++k) {
        int i4 = k * 512 + tid;                // < 2304 float4
        if (i4 < 2304) {
            int e = i4 * 4;
            int p = e / kP, q = e - p * kP;    // 96 % 4 == 0 -> same row
            float4 d4 = *(const float4*)(dbt + e);
            float mp = mrowf[p];
            float vv[4];
            vv[0] = (mp * mrowf[q + 0] != 0.f) ? __expf(-d4.x * d4.x * inv2s2) : 0.f;
            vv[1] = (mp * mrowf[q + 1] != 0.f) ? __expf(-d4.y * d4.y * inv2s2) : 0.f;
            vv[2] = (mp * mrowf[q + 2] != 0.f) ? __expf(-d4.z * d4.z * inv2s2) : 0.f;
            vv[3] = (mp * mrowf[q + 3] != 0.f) ? __expf(-d4.w * d4.w * inv2s2) : 0.f;
            #pragma unroll
            for (int j = 0; j < 4; ++j) {
                if (p == q + j) vv[j] += mp;
                aT[p * 100 + q + j] = vv[j];
            }
        }
    }
    __syncthreads();   // [B1] aT complete

    if (tid < kP) {
        float s = 0.f;
        for (int q = 0; q < kP; ++q) s += aT[q * 100 + tid];  // col == row sum
        s = fmaxf(s, 1e-8f);
        s = fmaxf(s * mrowf[tid], 1e-8f);
        dis[tid] = rsqrtf(s);
    }
    __syncthreads();   // [B2] dis ready

    // aL (bf16) = dis[p] * aT * dis[q]   (aL region disjoint from aT)
    #pragma unroll
    for (int k = 0; k < 5; ++k) {
        int i4 = k * 512 + tid;
        if (i4 < 2304) {
            int e = i4 * 4;
            int p = e / kP, q = e - p * kP;
            float dp = dis[p];
            bf16x4 ov;
            #pragma unroll
            for (int j = 0; j < 4; ++j)
                ov[j] = (bf16_t)(dp * aT[p * 100 + q + j] * dis[q + j]);
            *(bf16x4*)(aL + p * AS + q) = ov;
        }
    }
    __syncthreads();   // [B3] aT dead; safe to overwrite with yL

    // stage y -> yL (rows p = ty*3+i, cols d0..d0+7)
    #pragma unroll
    for (int i = 0; i < 3; ++i) {
        int p = ty * 3 + i;
        *(bf16x8*)(yL + p * YS + d0) = *(const bf16x8*)(ybt + p * kD + d0);
    }

    for (int l = 0; l < 2; ++l) {
        __syncthreads();   // [S1] yL ready (l=0) / yL updated + oLb reads done (l=1)

        // ---- GEMM1: h = yL * W  (K=128) ----
        f32x4 acc[3][2];
        #pragma unroll
        for (int mt = 0; mt < 3; ++mt) { acc[mt][0] = {0,0,0,0}; acc[mt][1] = {0,0,0,0}; }
        #pragma unroll
        for (int kt = 0; kt < 4; ++kt) {
            #pragma unroll
            for (int mt = 0; mt < 3; ++mt) {
                bf16x8 af = *(const bf16x8*)(yL + ((wm * 3 + mt) * 16 + fc) * YS + kt * 32 + fg * 8);
                acc[mt][0] = mfma16(af, wf[l][kt][0], acc[mt][0]);
                acc[mt][1] = mfma16(af, wf[l][kt][1], acc[mt][1]);
            }
        }
        // write h transposed: hT[e][p]  (yL untouched; prior oLb reads done at S1)
        #pragma unroll
        for (int mt = 0; mt < 3; ++mt)
            #pragma unroll
            for (int nn = 0; nn < 2; ++nn) {
                int e = (wn * 2 + nn) * 16 + fc;
                int p0 = (wm * 3 + mt) * 16 + fg * 4;
                bf16x4 hv = {(bf16_t)acc[mt][nn][0], (bf16_t)acc[mt][nn][1],
                             (bf16_t)acc[mt][nn][2], (bf16_t)acc[mt][nn][3]};
                *(bf16x4*)(hT + e * HS + p0) = hv;
            }
        __syncthreads();   // [S3] hT visible

        // ---- GEMM2: o = aL * h^T  (K=96) ----
        f32x4 acc2[3][2];
        #pragma unroll
        for (int mt = 0; mt < 3; ++mt) { acc2[mt][0] = {0,0,0,0}; acc2[mt][1] = {0,0,0,0}; }
        #pragma unroll
        for (int kt = 0; kt < 3; ++kt) {
            bf16x8 bf0 = *(const bf16x8*)(hT + ((wn * 2 + 0) * 16 + fc) * HS + kt * 32 + fg * 8);
            bf16x8 bf1 = *(const bf16x8*)(hT + ((wn * 2 + 1) * 16 + fc) * HS + kt * 32 + fg * 8);
            #pragma unroll
            for (int mt = 0; mt < 3; ++mt) {
                bf16x8 af = *(const bf16x8*)(aL + ((wm * 3 + mt) * 16 + fc) * AS + kt * 32 + fg * 8);
                acc2[mt][0] = mfma16(af, bf0, acc2[mt][0]);
                acc2[mt][1] = mfma16(af, bf1, acc2[mt][1]);
            }
        }
        __syncthreads();   // [S4] hT reads done before oLb overlay

        // scatter o -> oLb (bf16)
        #pragma unroll
        for (int mt = 0; mt < 3; ++mt)
            #pragma unroll
            for (int nn = 0; nn < 2; ++nn) {
                int d = (wn * 2 + nn) * 16 + fc;
                int p0 = (wm * 3 + mt) * 16 + fg * 4;
                oLb[(p0 + 0) * OS + d] = (bf16_t)acc2[mt][nn][0];
                oLb[(p0 + 1) * OS + d] = (bf16_t)acc2[mt][nn][1];
                oLb[(p0 + 2) * OS + d] = (bf16_t)acc2[mt][nn][2];
                oLb[(p0 + 3) * OS + d] = (bf16_t)acc2[mt][nn][3];
            }
        __syncthreads();   // [S5] oLb ready

        // ---- epilogue: relu+bias+mask, single-pass LN over D, residual ----
        const float* bl = bias + l * kD;
        const float* gl = gamma + l * kD;
        const float* bel = beta + l * kD;
        float4 bb0 = *(const float4*)(bl + d0), bb1 = *(const float4*)(bl + d0 + 4);
        float4 gg0 = *(const float4*)(gl + d0), gg1 = *(const float4*)(gl + d0 + 4);
        float4 be0 = *(const float4*)(bel + d0), be1 = *(const float4*)(bel + d0 + 4);
        float bb[8] = {bb0.x, bb0.y, bb0.z, bb0.w, bb1.x, bb1.y, bb1.z, bb1.w};
        float gg[8] = {gg0.x, gg0.y, gg0.z, gg0.w, gg1.x, gg1.y, gg1.z, gg1.w};
        float be[8] = {be0.x, be0.y, be0.z, be0.w, be1.x, be1.y, be1.z, be1.w};

        #pragma unroll
        for (int i = 0; i < 3; ++i) {
            int p = ty * 3 + i;
            float mpf = mrowf[p];
            bf16x4 o0 = *(const bf16x4*)(oLb + p * OS + d0);
            bf16x4 o1 = *(const bf16x4*)(oLb + p * OS + d0 + 4);
            bf16x8 yv = *(const bf16x8*)(yL + p * YS + d0);   // residual
            float v[8];
            #pragma unroll
            for (int j = 0; j < 4; ++j) {
                v[j]     = fmaxf((float)o0[j] + bb[j], 0.f) * mpf;
                v[j + 4] = fmaxf((float)o1[j] + bb[j + 4], 0.f) * mpf;
            }
            float s = 0.f, s2 = 0.f;
            #pragma unroll
            for (int j = 0; j < 8; ++j) { s += v[j]; s2 = fmaf(v[j], v[j], s2); }
            #pragma unroll
            for (int off = 8; off > 0; off >>= 1) {
                s += __shfl_xor(s, off);
                s2 += __shfl_xor(s2, off);
            }
            float mu = s * 0.0078125f;
            float varr = fmaxf(s2 * 0.0078125f - mu * mu, 0.f);
            float inv = rsqrtf(varr + 1e-5f);

            bf16x8 c;
            #pragma unroll
            for (int j = 0; j < 8; ++j)
                c[j] = (bf16_t)((float)yv[j] + (v[j] - mu) * inv * gg[j] + be[j]);

            if (l == 0) {
                // thread owns (p, d0..d0+7) exclusively; next S1 publishes
                *(bf16x8*)(yL + p * YS + d0) = c;
            } else {
                *(bf16x8*)(ybt + p * kD + d0) = c;
            }
        }
    }
}

// ---------------------------------------------------------------------------
extern "C" void kernel_launch(void* const* d_in, const int* in_sizes, int n_in,
                              void* d_out, int out_size, void* d_ws, size_t ws_size,
                              hipStream_t stream) {
    (void)in_sizes; (void)n_in; (void)out_size; (void)ws_size;

    const float* x = (const float*)d_in[0];
    const float* dist = (const float*)d_in[1];
    const unsigned char* mraw = (const unsigned char*)d_in[2];
    const float* W = (const float*)d_in[3];
    const float* bias = (const float*)d_in[4];
    const float* gamma = (const float*)d_in[5];
    const float* beta = (const float*)d_in[6];
    float* out = (float*)d_out;

    char* ws = (char*)d_ws;
    double* stats = (double*)ws;                 // 32 B
    int* mask = (int*)(ws + 64);                 // 6144 B
    bf16_t* wT = (bf16_t*)(ws + 8192);           // 65,536 B
    bf16_t* y = (bf16_t*)(ws + 81920);           // 47,185,920 B

    hipMemsetAsync(stats, 0, 32, stream);        // zero stats accumulators

    k_front<<<FRONT_BLOCKS, 256, 0, stream>>>(x, y, dist, mraw, mask, stats, W, wT);

    k_gcn<<<kBT, 512, 0, stream>>>(y, dist, mask, stats, wT, bias, gamma, beta);

    k_tout<<<dim3(kPD / 64, kB), 256, 0, stream>>>(y, out);
}

// Round 20
// 175.153 us; speedup vs baseline: 1.1915x; 1.1915x over previous
//
#include <hip/hip_runtime.h>
#include <math.h>

typedef __bf16 bf16_t;
typedef __bf16 bf16x8 __attribute__((ext_vector_type(8)));
typedef __bf16 bf16x4 __attribute__((ext_vector_type(4)));
typedef float f32x4 __attribute__((ext_vector_type(4)));

namespace {
constexpr int kB = 16;
constexpr int kT = 120;
constexpr int kP = 96;
constexpr int kD = 128;
constexpr int kBT = kB * kT;        // 1920
constexpr int kPP = kP * kP;        // 9216
constexpr int kPD = kP * kD;        // 12288
constexpr long long kND = (long long)kBT * kPP;  // 17,694,720

// k_front grid partition (r18-exact: STATS=1024; r19's 2048 cost +35 us)
constexpr int TIN_BLOCKS = (kPD / 64) * kB;       // 3072
constexpr int PREP_BLOCKS = 128;
constexpr int STATS_BLOCKS = 1024;
constexpr int FRONT_BLOCKS = TIN_BLOCKS + PREP_BLOCKS + STATS_BLOCKS;  // 4224

// k_gcn LDS layout (bytes) — round-7/9 structure (known-good):
constexpr int YS = 136;
constexpr int HS = 104;
constexpr int OS = 132;
constexpr int AS = 104;
constexpr int HT_OFF = 26112;
constexpr int AL_OFF = 52736;
constexpr int MROW_OFF = 72704;
constexpr int DIS_OFF = 73088;
constexpr int SMEM_B = 73472;       // -> 2 blocks/CU by LDS
}

__device__ __forceinline__ f32x4 mfma16(bf16x8 a, bf16x8 b, f32x4 c) {
    return __builtin_amdgcn_mfma_f32_16x16x32_bf16(a, b, c, 0, 0, 0);
}

// ---------------------------------------------------------------------------
// Kernel 1 (k_front): heterogeneous grid fusing three independent jobs.
//   blocks [0, 3072)      : transpose-in, x loads NON-TEMPORAL (r17-proven)
//   blocks [3072, 3200)   : W transpose->bf16; first block canonicalizes mask
//   blocks [3200, 4224)   : masked distance stats (NORMAL loads; 1024 blocks)
// stats accumulators zeroed by hipMemsetAsync; stats blocks dispatch LAST
// so dist is L3-freshest when k_gcn starts (r9-verified mechanism).
// ---------------------------------------------------------------------------
__global__ __launch_bounds__(256) void k_front(const float* __restrict__ x,
                                               bf16_t* __restrict__ y,
                                               const float* __restrict__ dist,
                                               const unsigned char* __restrict__ mraw,
                                               int* __restrict__ mask,
                                               double* __restrict__ stats,
                                               const float* __restrict__ W,
                                               bf16_t* __restrict__ wT) {
    __shared__ __align__(16) char sm[31104];
    const int bid = blockIdx.x;
    const int tid = threadIdx.x;

    if (bid < TIN_BLOCKS) {
        // ---- transpose-in role ----
        float* tile = (float*)sm;                  // [64][121] f32 = 30976 B
        int b = bid / (kPD / 64), pd0 = (bid % (kPD / 64)) * 64;
        const float* xb = x + ((long long)b * kPD + pd0) * kT;
        #pragma unroll
        for (int k = 0; k < 8; ++k) {
            int idx = k * 256 + tid;               // < 1920 = 64 rows * 30 float4
            if (idx < 1920) {
                int r = idx / 30, c = idx - r * 30;
                f32x4 v = __builtin_nontemporal_load((const f32x4*)(xb + r * kT + c * 4));
                tile[r * 121 + c * 4 + 0] = v[0];
                tile[r * 121 + c * 4 + 1] = v[1];
                tile[r * 121 + c * 4 + 2] = v[2];
                tile[r * 121 + c * 4 + 3] = v[3];
            }
        }
        __syncthreads();
        bf16_t* yb = y + (long long)b * kT * kPD + pd0;
        #pragma unroll
        for (int k = 0; k < 4; ++k) {
            int idx = k * 256 + tid;               // < 960 = 120 t * 8 dgroups
            if (idx < 960) {
                int t = idx >> 3, dg = idx & 7;
                bf16x8 o;
                #pragma unroll
                for (int j = 0; j < 8; ++j) o[j] = (bf16_t)tile[(dg * 8 + j) * 121 + t];
                *(bf16x8*)(yb + (long long)t * kPD + dg * 8) = o;
            }
        }
    } else if (bid < TIN_BLOCKS + PREP_BLOCKS) {
        // ---- W-prep role ----
        int pb = bid - TIN_BLOCKS;                 // 0..127
        int l = pb >> 6;
        int idx = (pb & 63) * 256 + tid;           // 0..16383
        int n = idx >> 7, k = idx & 127;
        wT[l * 16384 + n * 128 + k] = (bf16_t)W[l * 16384 + k * 128 + n];

        if (pb == 0) {
            const unsigned int* u32 = (const unsigned int*)mraw;
            unsigned int w0 = u32[0];
            int mode;
            if (w0 == 0x01010101u) mode = 0;       // 1-byte bool
            else if (w0 == 1u) mode = 1;           // int32
            else mode = 2;                          // float32
            for (int i = tid; i < kB * kP; i += 256) {
                int v;
                if (mode == 0)      v = (mraw[i] != 0);
                else if (mode == 1) v = (u32[i] != 0);
                else                v = (((const float*)mraw)[i] != 0.0f);
                mask[i] = v;
            }
        }
    } else {
        // ---- stats role (self-computes mask from mraw; no dependency) ----
        int sb = bid - TIN_BLOCKS - PREP_BLOCKS;   // 0..1023
        int* ml = (int*)sm;                        // [1536] = 6144 B
        double* sh = (double*)(sm + 6144);         // [256]  = 2048 B
        {
            const unsigned int* u32 = (const unsigned int*)mraw;
            unsigned int w0 = u32[0];
            int mode;
            if (w0 == 0x01010101u) mode = 0;
            else if (w0 == 1u) mode = 1;
            else mode = 2;
            for (int i = tid; i < kB * kP; i += 256) {
                int v;
                if (mode == 0)      v = (mraw[i] != 0);
                else if (mode == 1) v = (u32[i] != 0);
                else                v = (((const float*)mraw)[i] != 0.0f);
                ml[i] = v;
            }
        }
        __syncthreads();

        long long n4 = kND / 4;
        long long stride = (long long)STATS_BLOCKS * 256;
        double s = 0.0, s2 = 0.0;
        int cnt = 0;
        for (long long i4 = (long long)sb * 256 + tid; i4 < n4; i4 += stride) {
            int q0 = 4 * (int)(i4 % 24);
            long long r = i4 / 24;
            int p = (int)(r % 96);
            int b = (int)((r / 96) / kT);
            const int* mb = ml + b * kP;
            if (mb[p]) {
                float4 d4 = *(const float4*)(dist + i4 * 4);
                if (mb[q0 + 0]) { s += d4.x; s2 += (double)d4.x * d4.x; cnt++; }
                if (mb[q0 + 1]) { s += d4.y; s2 += (double)d4.y * d4.y; cnt++; }
                if (mb[q0 + 2]) { s += d4.z; s2 += (double)d4.z * d4.z; cnt++; }
                if (mb[q0 + 3]) { s += d4.w; s2 += (double)d4.w * d4.w; cnt++; }
            }
        }
        sh[tid] = s; __syncthreads();
        for (int off = 128; off > 0; off >>= 1) { if (tid < off) sh[tid] += sh[tid + off]; __syncthreads(); }
        if (tid == 0) atomicAdd(&stats[0], sh[0]);
        __syncthreads();
        sh[tid] = s2; __syncthreads();
        for (int off = 128; off > 0; off >>= 1) { if (tid < off) sh[tid] += sh[tid + off]; __syncthreads(); }
        if (tid == 0) atomicAdd(&stats[1], sh[0]);
        __syncthreads();
        sh[tid] = (double)cnt; __syncthreads();
        for (int off = 128; off > 0; off >>= 1) { if (tid < off) sh[tid] += sh[tid + off]; __syncthreads(); }
        if (tid == 0) atomicAdd(&stats[2], sh[0]);
    }
}

// ---------------------------------------------------------------------------
// Kernel 3: transpose out, y (B, T, PD) bf16 -> out (B, PD, T) f32.
// y loads and out stores NON-TEMPORAL (both dead after this kernel).
// ---------------------------------------------------------------------------
__global__ __launch_bounds__(256) void k_tout(const bf16_t* __restrict__ y,
                                              float* __restrict__ out) {
    __shared__ float tile[64 * 121];
    int b = blockIdx.y, pd0 = blockIdx.x * 64;
    int tid = threadIdx.x;
    const bf16_t* yb = y + (long long)b * kT * kPD + pd0;
    #pragma unroll
    for (int k = 0; k < 4; ++k) {
        int idx = k * 256 + tid;
        if (idx < 960) {
            int t = idx >> 3, dg = idx & 7;
            bf16x8 v = __builtin_nontemporal_load(
                (const bf16x8*)(yb + (long long)t * kPD + dg * 8));
            #pragma unroll
            for (int j = 0; j < 8; ++j) tile[(dg * 8 + j) * 121 + t] = (float)v[j];
        }
    }
    __syncthreads();
    float* ob = out + ((long long)b * kPD + pd0) * kT;
    #pragma unroll
    for (int k = 0; k < 8; ++k) {
        int idx = k * 256 + tid;
        if (idx < 1920) {
            int r = idx / 30, c = idx - r * 30;
            f32x4 v;
            v[0] = tile[r * 121 + c * 4 + 0];
            v[1] = tile[r * 121 + c * 4 + 1];
            v[2] = tile[r * 121 + c * 4 + 2];
            v[3] = tile[r * 121 + c * 4 + 3];
            __builtin_nontemporal_store(v, (f32x4*)(ob + r * kT + c * 4));
        }
    }
}

// ---------------------------------------------------------------------------
// Kernel 2: fused adjacency + 2-layer GCN — r7/r9 barrier skeleton, plus
// r19's confined trims (now measured against the r18 front):
//  * W fragments for BOTH layers prefetched before B0
//  * single-pass LN reduction (var = E[v^2] - mu^2; eps dominates)
// dist loads NORMAL.
// ---------------------------------------------------------------------------
__global__ __launch_bounds__(512, 2) void k_gcn(bf16_t* __restrict__ y,
                                                const float* __restrict__ dist,
                                                const int* __restrict__ mask,
                                                const double* __restrict__ stats,
                                                const bf16_t* __restrict__ wT,
                                                const float* __restrict__ bias,
                                                const float* __restrict__ gamma,
                                                const float* __restrict__ beta) {
    __shared__ __align__(16) char smem[SMEM_B];
    bf16_t* yL  = (bf16_t*)smem;                  // [96][YS]
    bf16_t* hT  = (bf16_t*)(smem + HT_OFF);       // [128][HS] (union)
    bf16_t* oLb = (bf16_t*)(smem + HT_OFF);       // [96][OS]  (union)
    float*  aT  = (float*)smem;                   // [96][100] adj phase only
    bf16_t* aL  = (bf16_t*)(smem + AL_OFF);       // [96][AS]
    float* mrowf = (float*)(smem + MROW_OFF);     // [96]
    float* dis   = (float*)(smem + DIS_OFF);      // [96]

    const int tid = threadIdx.x;
    const int tx = tid & 15, ty = tid >> 4;       // ty 0..31 (3 rows each)
    const int lane = tid & 63, w = tid >> 6;      // w 0..7
    const int wm = w >> 2, wn = w & 3;            // 2x4 wave grid
    const int fc = lane & 15, fg = lane >> 4;     // MFMA frag coords
    const int bt = blockIdx.x, b = bt / kT;
    const int d0 = tx * 8;

    bf16_t* ybt = y + (size_t)bt * kPD;
    const float* dbt = dist + (size_t)bt * kPP;

    // W fragments for BOTH layers -> registers (issued before B0; L2-resident,
    // drained by B0's existing vmcnt wait). 64 VGPRs.
    bf16x8 wf[2][4][2];
    #pragma unroll
    for (int l = 0; l < 2; ++l) {
        const bf16_t* wTl = wT + l * kD * kD;
        #pragma unroll
        for (int kt = 0; kt < 4; ++kt) {
            wf[l][kt][0] = *(const bf16x8*)(wTl + ((wn * 2 + 0) * 16 + fc) * kD + kt * 32 + fg * 8);
            wf[l][kt][1] = *(const bf16x8*)(wTl + ((wn * 2 + 1) * 16 + fc) * kD + kt * 32 + fg * 8);
        }
    }

    if (tid < kP) mrowf[tid] = (float)mask[b * kP + tid];

    // sigma -> 1/(2 sigma^2)  (tiny, L2-resident)
    double sn = stats[2];
    double mean = stats[0] / sn;
    double var = (stats[1] - sn * mean * mean) / (sn - 1.0);
    double sg = sqrt(var) + 1e-8;
    float inv2s2 = (float)(1.0 / (2.0 * sg * sg));

    __syncthreads();   // [B0] mrowf ready (drains mask + wf loads)

    // ---- adj phase: aT = exp(-d^2/(2s^2))*vm + eye*mask ----
    #pragma unroll
    for (int k = 0; k < 5; ++k) {
        int i4 = k * 512 + tid;                // < 2304 float4
        if (i4 < 2304) {
            int e = i4 * 4;
            int p = e / kP, q = e - p * kP;    // 96 % 4 == 0 -> same row
            float4 d4 = *(const float4*)(dbt + e);
            float mp = mrowf[p];
            float vv[4];
            vv[0] = (mp * mrowf[q + 0] != 0.f) ? __expf(-d4.x * d4.x * inv2s2) : 0.f;
            vv[1] = (mp * mrowf[q + 1] != 0.f) ? __expf(-d4.y * d4.y * inv2s2) : 0.f;
            vv[2] = (mp * mrowf[q + 2] != 0.f) ? __expf(-d4.z * d4.z * inv2s2) : 0.f;
            vv[3] = (mp * mrowf[q + 3] != 0.f) ? __expf(-d4.w * d4.w * inv2s2) : 0.f;
            #pragma unroll
            for (int j = 0; j < 4; ++j) {
                if (p == q + j) vv[j] += mp;
                aT[p * 100 + q + j] = vv[j];
            }
        }
    }
    __syncthreads();   // [B1] aT complete

    if (tid < kP) {
        float s = 0.f;
        for (int q = 0; q < kP; ++q) s += aT[q * 100 + tid];  // col == row sum
        s = fmaxf(s, 1e-8f);
        s = fmaxf(s * mrowf[tid], 1e-8f);
        dis[tid] = rsqrtf(s);
    }
    __syncthreads();   // [B2] dis ready

    // aL (bf16) = dis[p] * aT * dis[q]   (aL region disjoint from aT)
    #pragma unroll
    for (int k = 0; k < 5; ++k) {
        int i4 = k * 512 + tid;
        if (i4 < 2304) {
            int e = i4 * 4;
            int p = e / kP, q = e - p * kP;
            float dp = dis[p];
            bf16x4 ov;
            #pragma unroll
            for (int j = 0; j < 4; ++j)
                ov[j] = (bf16_t)(dp * aT[p * 100 + q + j] * dis[q + j]);
            *(bf16x4*)(aL + p * AS + q) = ov;
        }
    }
    __syncthreads();   // [B3] aT dead; safe to overwrite with yL

    // stage y -> yL (rows p = ty*3+i, cols d0..d0+7)
    #pragma unroll
    for (int i = 0; i < 3; ++i) {
        int p = ty * 3 + i;
        *(bf16x8*)(yL + p * YS + d0) = *(const bf16x8*)(ybt + p * kD + d0);
    }

    for (int l = 0; l < 2; ++l) {
        __syncthreads();   // [S1] yL ready (l=0) / yL updated + oLb reads done (l=1)

        // ---- GEMM1: h = yL * W  (K=128) ----
        f32x4 acc[3][2];
        #pragma unroll
        for (int mt = 0; mt < 3; ++mt) { acc[mt][0] = {0,0,0,0}; acc[mt][1] = {0,0,0,0}; }
        #pragma unroll
        for (int kt = 0; kt < 4; ++kt) {
            #pragma unroll
            for (int mt = 0; mt < 3; ++mt) {
                bf16x8 af = *(const bf16x8*)(yL + ((wm * 3 + mt) * 16 + fc) * YS + kt * 32 + fg * 8);
                acc[mt][0] = mfma16(af, wf[l][kt][0], acc[mt][0]);
                acc[mt][1] = mfma16(af, wf[l][kt][1], acc[mt][1]);
            }
        }
        // write h transposed: hT[e][p]  (yL untouched; prior oLb reads done at S1)
        #pragma unroll
        for (int mt = 0; mt < 3; ++mt)
            #pragma unroll
            for (int nn = 0; nn < 2; ++nn) {
                int e = (wn * 2 + nn) * 16 + fc;
                int p0 = (wm * 3 + mt) * 16 + fg * 4;
                bf16x4 hv = {(bf16_t)acc[mt][nn][0], (bf16_t)acc[mt][nn][1],
                             (bf16_t)acc[mt][nn][2], (bf16_t)acc[mt][nn][3]};
                *(bf16x4*)(hT + e * HS + p0) = hv;
            }
        __syncthreads();   // [S3] hT visible

        // ---- GEMM2: o = aL * h^T  (K=96) ----
        f32x4 acc2[3][2];
        #pragma unroll
        for (int mt = 0; mt < 3; ++mt) { acc2[mt][0] = {0,0,0,0}; acc2[mt][1] = {0,0,0,0}; }
        #pragma unroll
        for (int kt = 0; kt < 3; ++kt) {
            bf16x8 bf0 = *(const bf16x8*)(hT + ((wn * 2 + 0) * 16 + fc) * HS + kt * 32 + fg * 8);
            bf16x8 bf1 = *(const bf16x8*)(hT + ((wn * 2 + 1) * 16 + fc) * HS + kt * 32 + fg * 8);
            #pragma unroll
            for (int mt = 0; mt < 3; ++mt) {
                bf16x8 af = *(const bf16x8*)(aL + ((wm * 3 + mt) * 16 + fc) * AS + kt * 32 + fg * 8);
                acc2[mt][0] = mfma16(af, bf0, acc2[mt][0]);
                acc2[mt][1] = mfma16(af, bf1, acc2[mt][1]);
            }
        }
        __syncthreads();   // [S4] hT reads done before oLb overlay

        // scatter o -> oLb (bf16)
        #pragma unroll
        for (int mt = 0; mt < 3; ++mt)
            #pragma unroll
            for (int nn = 0; nn < 2; ++nn) {
                int d = (wn * 2 + nn) * 16 + fc;
                int p0 = (wm * 3 + mt) * 16 + fg * 4;
                oLb[(p0 + 0) * OS + d] = (bf16_t)acc2[mt][nn][0];
                oLb[(p0 + 1) * OS + d] = (bf16_t)acc2[mt][nn][1];
                oLb[(p0 + 2) * OS + d] = (bf16_t)acc2[mt][nn][2];
                oLb[(p0 + 3) * OS + d] = (bf16_t)acc2[mt][nn][3];
            }
        __syncthreads();   // [S5] oLb ready

        // ---- epilogue: relu+bias+mask, single-pass LN over D, residual ----
        const float* bl = bias + l * kD;
        const float* gl = gamma + l * kD;
        const float* bel = beta + l * kD;
        float4 bb0 = *(const float4*)(bl + d0), bb1 = *(const float4*)(bl + d0 + 4);
        float4 gg0 = *(const float4*)(gl + d0), gg1 = *(const float4*)(gl + d0 + 4);
        float4 be0 = *(const float4*)(bel + d0), be1 = *(const float4*)(bel + d0 + 4);
        float bb[8] = {bb0.x, bb0.y, bb0.z, bb0.w, bb1.x, bb1.y, bb1.z, bb1.w};
        float gg[8] = {gg0.x, gg0.y, gg0.z, gg0.w, gg1.x, gg1.y, gg1.z, gg1.w};
        float be[8] = {be0.x, be0.y, be0.z, be0.w, be1.x, be1.y, be1.z, be1.w};

        #pragma unroll
        for (int i = 0; i < 3; ++i) {
            int p = ty * 3 + i;
            float mpf = mrowf[p];
            bf16x4 o0 = *(const bf16x4*)(oLb + p * OS + d0);
            bf16x4 o1 = *(const bf16x4*)(oLb + p * OS + d0 + 4);
            bf16x8 yv = *(const bf16x8*)(yL + p * YS + d0);   // residual
            float v[8];
            #pragma unroll
            for (int j = 0; j < 4; ++j) {
                v[j]     = fmaxf((float)o0[j] + bb[j], 0.f) * mpf;
                v[j + 4] = fmaxf((float)o1[j] + bb[j + 4], 0.f) * mpf;
            }
            float s = 0.f, s2 = 0.f;
            #pragma unroll
            for (int j = 0; j < 8; ++j) { s += v[j]; s2 = fmaf(v[j], v[j], s2); }
            #pragma unroll
            for (int off = 8; off > 0; off >>= 1) {
                s += __shfl_xor(s, off);
                s2 += __shfl_xor(s2, off);
            }
            float mu = s * 0.0078125f;
            float varr = fmaxf(s2 * 0.0078125f - mu * mu, 0.f);
            float inv = rsqrtf(varr + 1e-5f);

            bf16x8 c;
            #pragma unroll
            for (int j = 0; j < 8; ++j)
                c[j] = (bf16_t)((float)yv[j] + (v[j] - mu) * inv * gg[j] + be[j]);

            if (l == 0) {
                // thread owns (p, d0..d0+7) exclusively; next S1 publishes
                *(bf16x8*)(yL + p * YS + d0) = c;
            } else {
                *(bf16x8*)(ybt + p * kD + d0) = c;
            }
        }
    }
}

// ---------------------------------------------------------------------------
extern "C" void kernel_launch(void* const* d_in, const int* in_sizes, int n_in,
                              void* d_out, int out_size, void* d_ws, size_t ws_size,
                              hipStream_t stream) {
    (void)in_sizes; (void)n_in; (void)out_size; (void)ws_size;

    const float* x = (const float*)d_in[0];
    const float* dist = (const float*)d_in[1];
    const unsigned char* mraw = (const unsigned char*)d_in[2];
    const float* W = (const float*)d_in[3];
    const float* bias = (const float*)d_in[4];
    const float* gamma = (const float*)d_in[5];
    const float* beta = (const float*)d_in[6];
    float* out = (float*)d_out;

    char* ws = (char*)d_ws;
    double* stats = (double*)ws;                 // 32 B
    int* mask = (int*)(ws + 64);                 // 6144 B
    bf16_t* wT = (bf16_t*)(ws + 8192);           // 65,536 B
    bf16_t* y = (bf16_t*)(ws + 81920);           // 47,185,920 B

    hipMemsetAsync(stats, 0, 32, stream);        // zero stats accumulators

    k_front<<<FRONT_BLOCKS, 256, 0, stream>>>(x, y, dist, mraw, mask, stats, W, wT);

    k_gcn<<<kBT, 512, 0, stream>>>(y, dist, mask, stats, wT, bias, gamma, beta);

    k_tout<<<dim3(kPD / 64, kB), 256, 0, stream>>>(y, out);
}

// Round 21
// 169.874 us; speedup vs baseline: 1.2286x; 1.0311x over previous
//
#include <hip/hip_runtime.h>
#include <math.h>

typedef __bf16 bf16_t;
typedef __bf16 bf16x8 __attribute__((ext_vector_type(8)));
typedef __bf16 bf16x4 __attribute__((ext_vector_type(4)));
typedef float f32x4 __attribute__((ext_vector_type(4)));

namespace {
constexpr int kB = 16;
constexpr int kT = 120;
constexpr int kP = 96;
constexpr int kD = 128;
constexpr int kBT = kB * kT;        // 1920
constexpr int kPP = kP * kP;        // 9216
constexpr int kPD = kP * kD;        // 12288
constexpr long long kND = (long long)kBT * kPP;  // 17,694,720

// k_front grid partition (r18-exact: session best, 170.0 us)
constexpr int TIN_BLOCKS = (kPD / 64) * kB;       // 3072
constexpr int PREP_BLOCKS = 128;
constexpr int STATS_BLOCKS = 1024;
constexpr int FRONT_BLOCKS = TIN_BLOCKS + PREP_BLOCKS + STATS_BLOCKS;  // 4224

// k_gcn LDS layout (bytes) — round-7/9 structure (known-good):
constexpr int YS = 136;
constexpr int HS = 104;
constexpr int OS = 132;
constexpr int AS = 104;
constexpr int HT_OFF = 26112;
constexpr int AL_OFF = 52736;
constexpr int MROW_OFF = 72704;
constexpr int DIS_OFF = 73088;
constexpr int SMEM_B = 73472;       // -> 2 blocks/CU by LDS
}

__device__ __forceinline__ f32x4 mfma16(bf16x8 a, bf16x8 b, f32x4 c) {
    return __builtin_amdgcn_mfma_f32_16x16x32_bf16(a, b, c, 0, 0, 0);
}

// ---------------------------------------------------------------------------
// Kernel 1 (k_front): heterogeneous grid fusing three independent jobs.
//   blocks [0, 3072)      : transpose-in, x loads NON-TEMPORAL (r17-proven:
//                           x never re-read; keeping it out of L3 preserves
//                           dist/y residency, front 96 -> ~78)
//   blocks [3072, 3200)   : W transpose->bf16; first block canonicalizes mask
//   blocks [3200, 4224)   : masked distance stats (NORMAL loads: dist re-read
//                           by k_gcn; 1024 blocks — 2048 regressed, r19)
// stats accumulators zeroed by hipMemsetAsync; stats blocks dispatch LAST
// so dist is L3-freshest when k_gcn starts (r9-verified mechanism).
// ---------------------------------------------------------------------------
__global__ __launch_bounds__(256) void k_front(const float* __restrict__ x,
                                               bf16_t* __restrict__ y,
                                               const float* __restrict__ dist,
                                               const unsigned char* __restrict__ mraw,
                                               int* __restrict__ mask,
                                               double* __restrict__ stats,
                                               const float* __restrict__ W,
                                               bf16_t* __restrict__ wT) {
    __shared__ __align__(16) char sm[31104];
    const int bid = blockIdx.x;
    const int tid = threadIdx.x;

    if (bid < TIN_BLOCKS) {
        // ---- transpose-in role ----
        float* tile = (float*)sm;                  // [64][121] f32 = 30976 B
        int b = bid / (kPD / 64), pd0 = (bid % (kPD / 64)) * 64;
        const float* xb = x + ((long long)b * kPD + pd0) * kT;
        #pragma unroll
        for (int k = 0; k < 8; ++k) {
            int idx = k * 256 + tid;               // < 1920 = 64 rows * 30 float4
            if (idx < 1920) {
                int r = idx / 30, c = idx - r * 30;
                f32x4 v = __builtin_nontemporal_load((const f32x4*)(xb + r * kT + c * 4));
                tile[r * 121 + c * 4 + 0] = v[0];
                tile[r * 121 + c * 4 + 1] = v[1];
                tile[r * 121 + c * 4 + 2] = v[2];
                tile[r * 121 + c * 4 + 3] = v[3];
            }
        }
        __syncthreads();
        bf16_t* yb = y + (long long)b * kT * kPD + pd0;
        #pragma unroll
        for (int k = 0; k < 4; ++k) {
            int idx = k * 256 + tid;               // < 960 = 120 t * 8 dgroups
            if (idx < 960) {
                int t = idx >> 3, dg = idx & 7;
                bf16x8 o;
                #pragma unroll
                for (int j = 0; j < 8; ++j) o[j] = (bf16_t)tile[(dg * 8 + j) * 121 + t];
                *(bf16x8*)(yb + (long long)t * kPD + dg * 8) = o;
            }
        }
    } else if (bid < TIN_BLOCKS + PREP_BLOCKS) {
        // ---- W-prep role ----
        int pb = bid - TIN_BLOCKS;                 // 0..127
        int l = pb >> 6;
        int idx = (pb & 63) * 256 + tid;           // 0..16383
        int n = idx >> 7, k = idx & 127;
        wT[l * 16384 + n * 128 + k] = (bf16_t)W[l * 16384 + k * 128 + n];

        if (pb == 0) {
            const unsigned int* u32 = (const unsigned int*)mraw;
            unsigned int w0 = u32[0];
            int mode;
            if (w0 == 0x01010101u) mode = 0;       // 1-byte bool
            else if (w0 == 1u) mode = 1;           // int32
            else mode = 2;                          // float32
            for (int i = tid; i < kB * kP; i += 256) {
                int v;
                if (mode == 0)      v = (mraw[i] != 0);
                else if (mode == 1) v = (u32[i] != 0);
                else                v = (((const float*)mraw)[i] != 0.0f);
                mask[i] = v;
            }
        }
    } else {
        // ---- stats role (self-computes mask from mraw; no dependency) ----
        int sb = bid - TIN_BLOCKS - PREP_BLOCKS;   // 0..1023
        int* ml = (int*)sm;                        // [1536] = 6144 B
        double* sh = (double*)(sm + 6144);         // [256]  = 2048 B
        {
            const unsigned int* u32 = (const unsigned int*)mraw;
            unsigned int w0 = u32[0];
            int mode;
            if (w0 == 0x01010101u) mode = 0;
            else if (w0 == 1u) mode = 1;
            else mode = 2;
            for (int i = tid; i < kB * kP; i += 256) {
                int v;
                if (mode == 0)      v = (mraw[i] != 0);
                else if (mode == 1) v = (u32[i] != 0);
                else                v = (((const float*)mraw)[i] != 0.0f);
                ml[i] = v;
            }
        }
        __syncthreads();

        long long n4 = kND / 4;
        long long stride = (long long)STATS_BLOCKS * 256;
        double s = 0.0, s2 = 0.0;
        int cnt = 0;
        for (long long i4 = (long long)sb * 256 + tid; i4 < n4; i4 += stride) {
            int q0 = 4 * (int)(i4 % 24);
            long long r = i4 / 24;
            int p = (int)(r % 96);
            int b = (int)((r / 96) / kT);
            const int* mb = ml + b * kP;
            if (mb[p]) {
                float4 d4 = *(const float4*)(dist + i4 * 4);
                if (mb[q0 + 0]) { s += d4.x; s2 += (double)d4.x * d4.x; cnt++; }
                if (mb[q0 + 1]) { s += d4.y; s2 += (double)d4.y * d4.y; cnt++; }
                if (mb[q0 + 2]) { s += d4.z; s2 += (double)d4.z * d4.z; cnt++; }
                if (mb[q0 + 3]) { s += d4.w; s2 += (double)d4.w * d4.w; cnt++; }
            }
        }
        sh[tid] = s; __syncthreads();
        for (int off = 128; off > 0; off >>= 1) { if (tid < off) sh[tid] += sh[tid + off]; __syncthreads(); }
        if (tid == 0) atomicAdd(&stats[0], sh[0]);
        __syncthreads();
        sh[tid] = s2; __syncthreads();
        for (int off = 128; off > 0; off >>= 1) { if (tid < off) sh[tid] += sh[tid + off]; __syncthreads(); }
        if (tid == 0) atomicAdd(&stats[1], sh[0]);
        __syncthreads();
        sh[tid] = (double)cnt; __syncthreads();
        for (int off = 128; off > 0; off >>= 1) { if (tid < off) sh[tid] += sh[tid + off]; __syncthreads(); }
        if (tid == 0) atomicAdd(&stats[2], sh[0]);
    }
}

// ---------------------------------------------------------------------------
// Kernel 3: transpose out, y (B, T, PD) bf16 -> out (B, PD, T) f32.
// y loads and out stores NON-TEMPORAL (both dead after this kernel).
// ---------------------------------------------------------------------------
__global__ __launch_bounds__(256) void k_tout(const bf16_t* __restrict__ y,
                                              float* __restrict__ out) {
    __shared__ float tile[64 * 121];
    int b = blockIdx.y, pd0 = blockIdx.x * 64;
    int tid = threadIdx.x;
    const bf16_t* yb = y + (long long)b * kT * kPD + pd0;
    #pragma unroll
    for (int k = 0; k < 4; ++k) {
        int idx = k * 256 + tid;
        if (idx < 960) {
            int t = idx >> 3, dg = idx & 7;
            bf16x8 v = __builtin_nontemporal_load(
                (const bf16x8*)(yb + (long long)t * kPD + dg * 8));
            #pragma unroll
            for (int j = 0; j < 8; ++j) tile[(dg * 8 + j) * 121 + t] = (float)v[j];
        }
    }
    __syncthreads();
    float* ob = out + ((long long)b * kPD + pd0) * kT;
    #pragma unroll
    for (int k = 0; k < 8; ++k) {
        int idx = k * 256 + tid;
        if (idx < 1920) {
            int r = idx / 30, c = idx - r * 30;
            f32x4 v;
            v[0] = tile[r * 121 + c * 4 + 0];
            v[1] = tile[r * 121 + c * 4 + 1];
            v[2] = tile[r * 121 + c * 4 + 2];
            v[3] = tile[r * 121 + c * 4 + 3];
            __builtin_nontemporal_store(v, (f32x4*)(ob + r * kT + c * 4));
        }
    }
}

// ---------------------------------------------------------------------------
// Kernel 2: fused adjacency + 2-layer GCN — r7/r9 structure (known-good).
// W fragments loaded per layer (r20 showed both-layers prefetch costs +5 us);
// two-pass LN (r20 showed single-pass is not a win); dist loads NORMAL
// (r17 NT experiment was neutral; normal is the simpler baseline).
// ---------------------------------------------------------------------------
__global__ __launch_bounds__(512, 2) void k_gcn(bf16_t* __restrict__ y,
                                                const float* __restrict__ dist,
                                                const int* __restrict__ mask,
                                                const double* __restrict__ stats,
                                                const bf16_t* __restrict__ wT,
                                                const float* __restrict__ bias,
                                                const float* __restrict__ gamma,
                                                const float* __restrict__ beta) {
    __shared__ __align__(16) char smem[SMEM_B];
    bf16_t* yL  = (bf16_t*)smem;                  // [96][YS]
    bf16_t* hT  = (bf16_t*)(smem + HT_OFF);       // [128][HS] (union)
    bf16_t* oLb = (bf16_t*)(smem + HT_OFF);       // [96][OS]  (union)
    float*  aT  = (float*)smem;                   // [96][100] adj phase only
    bf16_t* aL  = (bf16_t*)(smem + AL_OFF);       // [96][AS]
    float* mrowf = (float*)(smem + MROW_OFF);     // [96]
    float* dis   = (float*)(smem + DIS_OFF);      // [96]

    const int tid = threadIdx.x;
    const int tx = tid & 15, ty = tid >> 4;       // ty 0..31 (3 rows each)
    const int lane = tid & 63, w = tid >> 6;      // w 0..7
    const int wm = w >> 2, wn = w & 3;            // 2x4 wave grid
    const int fc = lane & 15, fg = lane >> 4;     // MFMA frag coords
    const int bt = blockIdx.x, b = bt / kT;
    const int d0 = tx * 8;

    bf16_t* ybt = y + (size_t)bt * kPD;
    const float* dbt = dist + (size_t)bt * kPP;

    if (tid < kP) mrowf[tid] = (float)mask[b * kP + tid];

    // sigma -> 1/(2 sigma^2)  (tiny, L2-resident)
    double sn = stats[2];
    double mean = stats[0] / sn;
    double var = (stats[1] - sn * mean * mean) / (sn - 1.0);
    double sg = sqrt(var) + 1e-8;
    float inv2s2 = (float)(1.0 / (2.0 * sg * sg));

    __syncthreads();   // [B0] mrowf ready

    // ---- adj phase: aT = exp(-d^2/(2s^2))*vm + eye*mask ----
    #pragma unroll
    for (int k = 0; k < 5; ++k) {
        int i4 = k * 512 + tid;                // < 2304 float4
        if (i4 < 2304) {
            int e = i4 * 4;
            int p = e / kP, q = e - p * kP;    // 96 % 4 == 0 -> same row
            float4 d4 = *(const float4*)(dbt + e);
            float mp = mrowf[p];
            float vv[4];
            vv[0] = (mp * mrowf[q + 0] != 0.f) ? __expf(-d4.x * d4.x * inv2s2) : 0.f;
            vv[1] = (mp * mrowf[q + 1] != 0.f) ? __expf(-d4.y * d4.y * inv2s2) : 0.f;
            vv[2] = (mp * mrowf[q + 2] != 0.f) ? __expf(-d4.z * d4.z * inv2s2) : 0.f;
            vv[3] = (mp * mrowf[q + 3] != 0.f) ? __expf(-d4.w * d4.w * inv2s2) : 0.f;
            #pragma unroll
            for (int j = 0; j < 4; ++j) {
                if (p == q + j) vv[j] += mp;
                aT[p * 100 + q + j] = vv[j];
            }
        }
    }
    __syncthreads();   // [B1] aT complete

    if (tid < kP) {
        float s = 0.f;
        for (int q = 0; q < kP; ++q) s += aT[q * 100 + tid];  // col == row sum
        s = fmaxf(s, 1e-8f);
        s = fmaxf(s * mrowf[tid], 1e-8f);
        dis[tid] = rsqrtf(s);
    }
    __syncthreads();   // [B2] dis ready

    // aL (bf16) = dis[p] * aT * dis[q]   (aL region disjoint from aT)
    #pragma unroll
    for (int k = 0; k < 5; ++k) {
        int i4 = k * 512 + tid;
        if (i4 < 2304) {
            int e = i4 * 4;
            int p = e / kP, q = e - p * kP;
            float dp = dis[p];
            bf16x4 ov;
            #pragma unroll
            for (int j = 0; j < 4; ++j)
                ov[j] = (bf16_t)(dp * aT[p * 100 + q + j] * dis[q + j]);
            *(bf16x4*)(aL + p * AS + q) = ov;
        }
    }
    __syncthreads();   // [B3] aT dead; safe to overwrite with yL

    // stage y -> yL (rows p = ty*3+i, cols d0..d0+7)
    #pragma unroll
    for (int i = 0; i < 3; ++i) {
        int p = ty * 3 + i;
        *(bf16x8*)(yL + p * YS + d0) = *(const bf16x8*)(ybt + p * kD + d0);
    }

    for (int l = 0; l < 2; ++l) {
        // W fragments -> registers (wave wn owns n-tiles wn*2, wn*2+1)
        const bf16_t* wTl = wT + l * kD * kD;
        bf16x8 wf[4][2];
        #pragma unroll
        for (int kt = 0; kt < 4; ++kt) {
            wf[kt][0] = *(const bf16x8*)(wTl + ((wn * 2 + 0) * 16 + fc) * kD + kt * 32 + fg * 8);
            wf[kt][1] = *(const bf16x8*)(wTl + ((wn * 2 + 1) * 16 + fc) * kD + kt * 32 + fg * 8);
        }
        __syncthreads();   // [S1] yL ready (l=0) / yL updated + oLb reads done (l=1)

        // ---- GEMM1: h = yL * W  (K=128) ----
        f32x4 acc[3][2];
        #pragma unroll
        for (int mt = 0; mt < 3; ++mt) { acc[mt][0] = {0,0,0,0}; acc[mt][1] = {0,0,0,0}; }
        #pragma unroll
        for (int kt = 0; kt < 4; ++kt) {
            #pragma unroll
            for (int mt = 0; mt < 3; ++mt) {
                bf16x8 af = *(const bf16x8*)(yL + ((wm * 3 + mt) * 16 + fc) * YS + kt * 32 + fg * 8);
                acc[mt][0] = mfma16(af, wf[kt][0], acc[mt][0]);
                acc[mt][1] = mfma16(af, wf[kt][1], acc[mt][1]);
            }
        }
        // write h transposed: hT[e][p]  (yL untouched; prior oLb reads done at S1)
        #pragma unroll
        for (int mt = 0; mt < 3; ++mt)
            #pragma unroll
            for (int nn = 0; nn < 2; ++nn) {
                int e = (wn * 2 + nn) * 16 + fc;
                int p0 = (wm * 3 + mt) * 16 + fg * 4;
                bf16x4 hv = {(bf16_t)acc[mt][nn][0], (bf16_t)acc[mt][nn][1],
                             (bf16_t)acc[mt][nn][2], (bf16_t)acc[mt][nn][3]};
                *(bf16x4*)(hT + e * HS + p0) = hv;
            }
        __syncthreads();   // [S3] hT visible

        // ---- GEMM2: o = aL * h^T  (K=96) ----
        f32x4 acc2[3][2];
        #pragma unroll
        for (int mt = 0; mt < 3; ++mt) { acc2[mt][0] = {0,0,0,0}; acc2[mt][1] = {0,0,0,0}; }
        #pragma unroll
        for (int kt = 0; kt < 3; ++kt) {
            bf16x8 bf0 = *(const bf16x8*)(hT + ((wn * 2 + 0) * 16 + fc) * HS + kt * 32 + fg * 8);
            bf16x8 bf1 = *(const bf16x8*)(hT + ((wn * 2 + 1) * 16 + fc) * HS + kt * 32 + fg * 8);
            #pragma unroll
            for (int mt = 0; mt < 3; ++mt) {
                bf16x8 af = *(const bf16x8*)(aL + ((wm * 3 + mt) * 16 + fc) * AS + kt * 32 + fg * 8);
                acc2[mt][0] = mfma16(af, bf0, acc2[mt][0]);
                acc2[mt][1] = mfma16(af, bf1, acc2[mt][1]);
            }
        }
        __syncthreads();   // [S4] hT reads done before oLb overlay

        // scatter o -> oLb (bf16)
        #pragma unroll
        for (int mt = 0; mt < 3; ++mt)
            #pragma unroll
            for (int nn = 0; nn < 2; ++nn) {
                int d = (wn * 2 + nn) * 16 + fc;
                int p0 = (wm * 3 + mt) * 16 + fg * 4;
                oLb[(p0 + 0) * OS + d] = (bf16_t)acc2[mt][nn][0];
                oLb[(p0 + 1) * OS + d] = (bf16_t)acc2[mt][nn][1];
                oLb[(p0 + 2) * OS + d] = (bf16_t)acc2[mt][nn][2];
                oLb[(p0 + 3) * OS + d] = (bf16_t)acc2[mt][nn][3];
            }
        __syncthreads();   // [S5] oLb ready

        // ---- epilogue: relu+bias+mask, LN over D, residual from yL ----
        const float* bl = bias + l * kD;
        const float* gl = gamma + l * kD;
        const float* bel = beta + l * kD;
        float4 bb0 = *(const float4*)(bl + d0), bb1 = *(const float4*)(bl + d0 + 4);
        float4 gg0 = *(const float4*)(gl + d0), gg1 = *(const float4*)(gl + d0 + 4);
        float4 be0 = *(const float4*)(bel + d0), be1 = *(const float4*)(bel + d0 + 4);
        float bb[8] = {bb0.x, bb0.y, bb0.z, bb0.w, bb1.x, bb1.y, bb1.z, bb1.w};
        float gg[8] = {gg0.x, gg0.y, gg0.z, gg0.w, gg1.x, gg1.y, gg1.z, gg1.w};
        float be[8] = {be0.x, be0.y, be0.z, be0.w, be1.x, be1.y, be1.z, be1.w};

        #pragma unroll
        for (int i = 0; i < 3; ++i) {
            int p = ty * 3 + i;
            float mpf = mrowf[p];
            bf16x4 o0 = *(const bf16x4*)(oLb + p * OS + d0);
            bf16x4 o1 = *(const bf16x4*)(oLb + p * OS + d0 + 4);
            bf16x8 yv = *(const bf16x8*)(yL + p * YS + d0);   // residual
            float v[8];
            #pragma unroll
            for (int j = 0; j < 4; ++j) {
                v[j]     = fmaxf((float)o0[j] + bb[j], 0.f) * mpf;
                v[j + 4] = fmaxf((float)o1[j] + bb[j + 4], 0.f) * mpf;
            }
            float s = v[0] + v[1] + v[2] + v[3] + v[4] + v[5] + v[6] + v[7];
            s += __shfl_xor(s, 8);
            s += __shfl_xor(s, 4);
            s += __shfl_xor(s, 2);
            s += __shfl_xor(s, 1);
            float mu = s * 0.0078125f;

            float ss = 0.f;
            #pragma unroll
            for (int j = 0; j < 8; ++j) { float dv = v[j] - mu; ss += dv * dv; }
            ss += __shfl_xor(ss, 8);
            ss += __shfl_xor(ss, 4);
            ss += __shfl_xor(ss, 2);
            ss += __shfl_xor(ss, 1);
            float inv = rsqrtf(ss * 0.0078125f + 1e-5f);

            bf16x8 c;
            #pragma unroll
            for (int j = 0; j < 8; ++j)
                c[j] = (bf16_t)((float)yv[j] + (v[j] - mu) * inv * gg[j] + be[j]);

            if (l == 0) {
                // thread owns (p, d0..d0+7) exclusively; next S1 publishes
                *(bf16x8*)(yL + p * YS + d0) = c;
            } else {
                *(bf16x8*)(ybt + p * kD + d0) = c;
            }
        }
    }
}

// ---------------------------------------------------------------------------
extern "C" void kernel_launch(void* const* d_in, const int* in_sizes, int n_in,
                              void* d_out, int out_size, void* d_ws, size_t ws_size,
                              hipStream_t stream) {
    (void)in_sizes; (void)n_in; (void)out_size; (void)ws_size;

    const float* x = (const float*)d_in[0];
    const float* dist = (const float*)d_in[1];
    const unsigned char* mraw = (const unsigned char*)d_in[2];
    const float* W = (const float*)d_in[3];
    const float* bias = (const float*)d_in[4];
    const float* gamma = (const float*)d_in[5];
    const float* beta = (const float*)d_in[6];
    float* out = (float*)d_out;

    char* ws = (char*)d_ws;
    double* stats = (double*)ws;                 // 32 B
    int* mask = (int*)(ws + 64);                 // 6144 B
    bf16_t* wT = (bf16_t*)(ws + 8192);           // 65,536 B
    bf16_t* y = (bf16_t*)(ws + 81920);           // 47,185,920 B

    hipMemsetAsync(stats, 0, 32, stream);        // zero stats accumulators

    k_front<<<FRONT_BLOCKS, 256, 0, stream>>>(x, y, dist, mraw, mask, stats, W, wT);

    k_gcn<<<kBT, 512, 0, stream>>>(y, dist, mask, stats, wT, bias, gamma, beta);

    k_tout<<<dim3(kPD / 64, kB), 256, 0, stream>>>(y, out);
}